// Round 7
// baseline (223.560 us; speedup 1.0000x reference)
//
#include <hip/hip_runtime.h>
#include <hip/hip_fp16.h>
#include <cstdint>
#include <cstddef>

#define BB 4
#define CC 256
#define NN 4096
#define EPS_NORM 2.220446049250313e-16f
#define EPS_MIN 1e-5f

typedef __attribute__((ext_vector_type(8))) short short8;
typedef __attribute__((ext_vector_type(4))) float floatx4;

__device__ __forceinline__ unsigned short f2bf(float f) {
    unsigned u = __float_as_uint(f);
    u += 0x7FFFu + ((u >> 16) & 1u);   // RNE
    return (unsigned short)(u >> 16);
}
__device__ __forceinline__ void async_cp16(const void* g, void* l) {
    __builtin_amdgcn_global_load_lds(
        (const __attribute__((address_space(1))) unsigned int*)g,
        (__attribute__((address_space(3))) unsigned int*)l, 16, 0, 0);
}

// ---- K1: per-channel spatial mean of Y (float4); also zero sums ------------
__global__ void kmean(const float* __restrict__ Y, float* __restrict__ ymean,
                      float* __restrict__ sums) {
    if (blockIdx.x == 0 && threadIdx.x < BB) sums[threadIdx.x] = 0.f;
    int bc = blockIdx.x;  // b*CC + c
    const float4* p = (const float4*)(Y + (size_t)bc * NN);
    float s = 0.f;
    for (int k = threadIdx.x; k < NN / 4; k += 256) {
        float4 v = p[k];
        s += (v.x + v.y) + (v.z + v.w);
    }
    __shared__ float red[256];
    red[threadIdx.x] = s; __syncthreads();
    for (int st = 128; st > 0; st >>= 1) {
        if (threadIdx.x < st) red[threadIdx.x] += red[threadIdx.x + st];
        __syncthreads();
    }
    if (threadIdx.x == 0) ymean[bc] = red[0] * (1.0f / NN);
}

// ------- K2: fused norm + normalize + transpose -> bf16 [B,N,C] -------------
__global__ __launch_bounds__(256)
void kfuse(const float* __restrict__ X, const float* __restrict__ Y,
           const float* __restrict__ ymean,
           unsigned short* __restrict__ XnT, unsigned short* __restrict__ YnT) {
    int b = blockIdx.y >> 1, which = blockIdx.y & 1;
    const float* src = which ? Y : X;
    unsigned short* dst = which ? YnT : XnT;
    int n0 = blockIdx.x * 64;
    int tx = threadIdx.x & 63, ty = threadIdx.x >> 6;
    __shared__ float mean_s[CC];
    __shared__ float red[4][64];
    __shared__ float invn[64];
    __shared__ float tile[64][65];
    mean_s[threadIdx.x] = ymean[b * CC + threadIdx.x];
    __syncthreads();
    float vreg[64];
    float s = 0.f;
    #pragma unroll
    for (int k = 0; k < 64; ++k) {
        int c = ty + 4 * k;
        float v = src[(((size_t)b * CC + c) << 12) + n0 + tx] - mean_s[c];
        vreg[k] = v;
        s += v * v;
    }
    red[ty][tx] = s; __syncthreads();
    if (ty == 0) {
        float t = red[0][tx] + red[1][tx] + red[2][tx] + red[3][tx];
        invn[tx] = 1.0f / (sqrtf(t) + EPS_NORM);
    }
    __syncthreads();
    float inv = invn[tx];
    for (int cb = 0; cb < 4; ++cb) {
        if (cb) __syncthreads();
        #pragma unroll
        for (int kk = 0; kk < 16; ++kk) {
            tile[4 * kk + ty][tx] = vreg[cb * 16 + kk] * inv;
        }
        __syncthreads();
        #pragma unroll
        for (int it = 0; it < 16; ++it) {
            int nl = ty + it * 4;
            dst[((size_t)(b * NN + n0 + nl)) * CC + cb * 64 + tx] = f2bf(tile[tx][nl]);
        }
    }
}

// -------- krow: 64-row panel GEMM, A-frags in 64 VGPRs, 4-slot B pipeline ---
// Block = 256 thr (4 waves 2x2), tile 64 rows x 2048 cols (j-half).
// Grid 512 = 2 blocks/CU: barrier stalls of one block hidden by the other.
// A (64x256) staged once into slots 2-3, frags hoisted (16 short8 = 64 VGPR),
// region recycled as B slots. B rotates 4 x 16 KiB slots, prefetch depth 3,
// steady s_waitcnt vmcnt(12); prologue uses deterministic __syncthreads
// drains (no counted-wait ordering assumptions).
// MODE 1: row-min of d. MODE 2: row-sum of exp. MODE 3: col-max -> colpart.
template <int MODE>
__global__ __launch_bounds__(256, 2)
void krow(const unsigned short* __restrict__ Aptr, const unsigned short* __restrict__ Bptr,
          const float* __restrict__ rowA, const float* __restrict__ rowB,
          float* __restrict__ partial, float* __restrict__ colpart) {
    const int bid = blockIdx.x;
    const int b = (bid >> 1) & 3;       // xcd = bid&7 -> (b,jh): batch pinned to 2 XCDs
    const int jh = bid & 1;
    const int ip = bid >> 3;            // 0..63
    const int i0 = ip * 64, j0 = jh * 2048;
    const int tid = threadIdx.x, lane = tid & 63, wave = tid >> 6;
    const int wm = wave >> 1, wn = wave & 1, l15 = lane & 15, quad = lane >> 4;

    __shared__ unsigned short Bs[4 * 8192];   // 64 KiB: 4 B-slots (2-3 hold A first)
    __shared__ float scr3[4 * 4 * 64];        // 4 KiB: mode3 jt-group staging / epilogue

    // ---- per-row alpha/beta straight into registers ------------------------
    float pax[2][4], pay[2][4];
    if (MODE >= 2) {
        #pragma unroll
        for (int m = 0; m < 2; ++m)
            #pragma unroll
            for (int r = 0; r < 4; ++r) {
                const int i = b * NN + i0 + wm * 32 + m * 16 + quad * 4 + r;
                const float a = rowA[i];
                pax[m][r] = a;
                pay[m][r] = (MODE == 2) ? (10.0f - a) : (rowB[i] - a);
            }
    }

    const int rl = lane >> 3, pos = lane & 7, cbx = pos ^ rl;

    // ---- stage A (64x256) once into slots 2+3 region: kc = wave ------------
    {
        const unsigned short* gAl = Aptr + ((size_t)b * NN + i0 + rl) * CC + wave * 64 + cbx * 8;
        unsigned short* lA = Bs + 2 * 8192 + wave * 4096;
        #pragma unroll
        for (int seg = 0; seg < 8; ++seg)
            async_cp16(gAl + (size_t)seg * 8 * CC, lA + seg * 8 * 64);
    }

    // ---- B staging: slot s&3, 128 j-rows x 64 k per stage ------------------
    const unsigned short* gBl = Bptr + ((size_t)b * NN + j0 + wave * 32 + rl) * CC + cbx * 8;
#define STAGE_B(s) do { \
        const unsigned short* gs_ = gBl + (size_t)((s) >> 2) * 128 * CC + ((s) & 3) * 64; \
        unsigned short* lb_ = Bs + ((s) & 3) * 8192 + wave * 2048; \
        async_cp16(gs_ + (size_t)0 * 8 * CC, lb_ + 0 * 8 * 64); \
        async_cp16(gs_ + (size_t)1 * 8 * CC, lb_ + 1 * 8 * 64); \
        async_cp16(gs_ + (size_t)2 * 8 * CC, lb_ + 2 * 8 * 64); \
        async_cp16(gs_ + (size_t)3 * 8 * CC, lb_ + 3 * 8 * 64); \
    } while (0)

    STAGE_B(0);
    STAGE_B(1);
    __syncthreads();                 // deterministic full drain: A, B0, B1, pa/pb landed

    // ---- hoist A fragments: 4 kc x 2 kk-halves x 2 m = 16 short8 (64 VGPR) -
    short8 af[4][4];
    {
        const unsigned short* Ar = Bs + 2 * 8192;
        #pragma unroll
        for (int kc = 0; kc < 4; ++kc)
            #pragma unroll
            for (int h = 0; h < 2; ++h)
                #pragma unroll
                for (int m = 0; m < 2; ++m)
                    af[kc][h * 2 + m] = *(const short8*)&Ar[kc * 4096 +
                        (wm * 32 + m * 16 + l15) * 64 + (((quad + 4 * h) ^ (l15 & 7)) << 3)];
    }
    __syncthreads();                 // all af ds_reads complete -> A region free
    STAGE_B(2);
    STAGE_B(3);

    floatx4 acc[2][4];
    #pragma unroll
    for (int m = 0; m < 2; ++m)
        #pragma unroll
        for (int ns = 0; ns < 4; ++ns) acc[m][ns] = (floatx4){0.f, 0.f, 0.f, 0.f};
    float rm[2][4];
    #pragma unroll
    for (int m = 0; m < 2; ++m)
        #pragma unroll
        for (int r = 0; r < 4; ++r) rm[m][r] = (MODE == 1) ? 1e30f : 0.f;

    // mode3: flush 4-jt group g from scr3 to colpart (coalesced float4)
#define FLUSH(g_) do { \
        const int t4_ = tid * 4; \
        const int wg_ = t4_ >> 8, jtl_ = (t4_ >> 6) & 3, c_ = t4_ & 63; \
        float4 fv_ = *(const float4*)&scr3[t4_]; \
        *(float4*)&colpart[((size_t)(b * 128 + ip * 2 + (wg_ >> 1))) * NN + j0 + \
                           ((g_) * 4 + jtl_) * 128 + (wg_ & 1) * 64 + c_] = fv_; \
    } while (0)

#define STEP_BODY(ut_, kc_, VMN_, DOSTAGE_) do { \
        asm volatile("" ::: "memory"); \
        __builtin_amdgcn_s_barrier(); \
        asm volatile("" ::: "memory"); \
        if (MODE == 3 && (kc_) == 0 && (ut_) > 0 && ((ut_) & 3) == 0) FLUSH((ut_) / 4 - 1); \
        if (DOSTAGE_) STAGE_B((ut_) * 4 + (kc_) + 3); \
        asm volatile("s_waitcnt vmcnt(" #VMN_ ")" ::: "memory"); \
        __builtin_amdgcn_s_barrier(); \
        asm volatile("" ::: "memory"); \
        const unsigned short* Bp_ = Bs + (kc_) * 8192; \
        _Pragma("unroll") \
        for (int h = 0; h < 2; ++h) { \
            short8 bf[4]; \
            const int sw_ = (((quad + 4 * h) ^ (l15 & 7)) << 3); \
            _Pragma("unroll") \
            for (int s = 0; s < 4; ++s) \
                bf[s] = *(const short8*)&Bp_[(wn * 64 + s * 16 + l15) * 64 + sw_]; \
            _Pragma("unroll") \
            for (int m = 0; m < 2; ++m) \
                _Pragma("unroll") \
                for (int ns = 0; ns < 4; ++ns) \
                    acc[m][ns] = __builtin_amdgcn_mfma_f32_16x16x32_bf16( \
                        af[kc_][h * 2 + m], bf[ns], acc[m][ns], 0, 0, 0); \
        } \
        if ((kc_) == 3) { \
            const int jt_ = (ut_); \
            if (MODE == 1) { \
                _Pragma("unroll") \
                for (int m = 0; m < 2; ++m) \
                    _Pragma("unroll") \
                    for (int r = 0; r < 4; ++r) { \
                        float mn_ = 1.0f - acc[m][0][r]; \
                        _Pragma("unroll") \
                        for (int ns = 1; ns < 4; ++ns) mn_ = fminf(mn_, 1.0f - acc[m][ns][r]); \
                        rm[m][r] = fminf(rm[m][r], mn_); \
                    } \
            } else if (MODE == 2) { \
                _Pragma("unroll") \
                for (int m = 0; m < 2; ++m) \
                    _Pragma("unroll") \
                    for (int r = 0; r < 4; ++r) { \
                        float s_ = 0.f; \
                        _Pragma("unroll") \
                        for (int ns = 0; ns < 4; ++ns) \
                            s_ += __expf(fmaf(pax[m][r], acc[m][ns][r], pay[m][r])); \
                        rm[m][r] += s_; \
                    } \
            } else { \
                _Pragma("unroll") \
                for (int ns = 0; ns < 4; ++ns) { \
                    float v_ = -1e30f; \
                    _Pragma("unroll") \
                    for (int m = 0; m < 2; ++m) \
                        _Pragma("unroll") \
                        for (int r = 0; r < 4; ++r) \
                            v_ = fmaxf(v_, fmaf(pax[m][r], acc[m][ns][r], pay[m][r])); \
                    v_ = fmaxf(v_, __shfl_xor(v_, 16)); \
                    v_ = fmaxf(v_, __shfl_xor(v_, 32)); \
                    if (quad == 0) \
                        scr3[((wm * 2 + wn) * 4 + (jt_ & 3)) * 64 + ns * 16 + l15] = v_; \
                } \
                asm volatile("s_waitcnt lgkmcnt(0)" ::: "memory"); \
            } \
            _Pragma("unroll") \
            for (int m = 0; m < 2; ++m) \
                _Pragma("unroll") \
                for (int ns = 0; ns < 4; ++ns) acc[m][ns] = (floatx4){0.f, 0.f, 0.f, 0.f}; \
        } \
    } while (0)

    for (int ut = 0; ut < 15; ++ut) {
        STEP_BODY(ut, 0, 12, (ut > 0));
        STEP_BODY(ut, 1, 12, true);
        STEP_BODY(ut, 2, 12, true);
        STEP_BODY(ut, 3, 12, true);
    }
    STEP_BODY(15, 0, 12, true);    // u=60, stages 63
    STEP_BODY(15, 1, 8,  false);
    STEP_BODY(15, 2, 4,  false);
    STEP_BODY(15, 3, 0,  false);
#undef STEP_BODY
#undef STAGE_B

    // ---- block epilogue ----------------------------------------------------
    if (MODE <= 2) {
        #pragma unroll
        for (int m = 0; m < 2; ++m)
            #pragma unroll
            for (int r = 0; r < 4; ++r) {
                float v = rm[m][r];
                if (MODE == 1) {
                    v = fminf(v, __shfl_xor(v, 1)); v = fminf(v, __shfl_xor(v, 2));
                    v = fminf(v, __shfl_xor(v, 4)); v = fminf(v, __shfl_xor(v, 8));
                } else {
                    v += __shfl_xor(v, 1); v += __shfl_xor(v, 2);
                    v += __shfl_xor(v, 4); v += __shfl_xor(v, 8);
                }
                if (l15 == 0)
                    scr3[(wm * 32 + m * 16 + quad * 4 + r) * 2 + wn] = v;
            }
        __syncthreads();
        if (tid < 64) {
            float v = (MODE == 1) ? fminf(scr3[tid * 2], scr3[tid * 2 + 1])
                                  : (scr3[tid * 2] + scr3[tid * 2 + 1]);
            partial[((size_t)(b * 2 + jh)) * NN + i0 + tid] = v;
        }
    } else {
        __syncthreads();
        FLUSH(3);      // jt 12..15
    }
#undef FLUSH
}

// ---- reduce partial row-min over 2 j-halves -> alpha -----------------------
__global__ void kredA(const float* __restrict__ partial, float* __restrict__ rowA) {
    int idx = blockIdx.x * 256 + threadIdx.x;      // over BB*NN
    int b = idx >> 12, i = idx & (NN - 1);
    float m = fminf(partial[((size_t)(b * 2)) * NN + i],
                    partial[((size_t)(b * 2 + 1)) * NN + i]);
    rowA[idx] = 10.0f / (m + EPS_MIN);
}

// ---- reduce partial row-sum over 2 j-halves -> beta ------------------------
__global__ void kredB(const float* __restrict__ partial, float* __restrict__ rowB) {
    int idx = blockIdx.x * 256 + threadIdx.x;
    int b = idx >> 12, i = idx & (NN - 1);
    float s = partial[((size_t)(b * 2)) * NN + i] +
              partial[((size_t)(b * 2 + 1)) * NN + i];
    rowB[idx] = 10.0f - __logf(s);
}

// ---- reduce colpart over 128 partial rows -> exp -> sum per batch ----------
__global__ void kredC(const float* __restrict__ colpart, float* __restrict__ sums) {
    int b = blockIdx.y;
    int j = blockIdx.x * 256 + threadIdx.x;
    float m = -1e30f;
    #pragma unroll 4
    for (int p = 0; p < 128; ++p)
        m = fmaxf(m, colpart[((size_t)(b * 128 + p)) * NN + j]);
    float e = __expf(m);
    __shared__ float red[256];
    red[threadIdx.x] = e; __syncthreads();
    for (int st = 128; st > 0; st >>= 1) {
        if (threadIdx.x < st) red[threadIdx.x] += red[threadIdx.x + st];
        __syncthreads();
    }
    if (threadIdx.x == 0) atomicAdd(&sums[b], red[0]);
}

__global__ void kfinal2(const float* __restrict__ sums, float* __restrict__ out) {
    int t = threadIdx.x;
    if (t < BB) out[t] = logf((float)NN) - logf(sums[t]);
}

extern "C" void kernel_launch(void* const* d_in, const int* in_sizes, int n_in,
                              void* d_out, int out_size, void* d_ws, size_t ws_size,
                              hipStream_t stream) {
    const float* X = (const float*)d_in[0];
    const float* Y = (const float*)d_in[1];
    float* out = (float*)d_out;

    char* w = (char*)d_ws;
    float* ymean        = (float*)(w + 0);                  //   4 KiB
    float* sums         = (float*)(w + 4096);               //  tiny
    float* rowA         = (float*)(w + 8192);               //  64 KiB
    float* rowB         = (float*)(w + 73728);              //  64 KiB
    float* partial      = (float*)(w + 139264);             // 128 KiB
    float* colpart      = (float*)(w + 270336);             //   8 MiB
    unsigned short* XnT = (unsigned short*)(w + 8658944);   //   8 MiB
    unsigned short* YnT = (unsigned short*)(w + 17047552);  //   8 MiB (total ~25.4 MiB)

    kmean<<<dim3(BB * CC), 256, 0, stream>>>(Y, ymean, sums);
    kfuse<<<dim3(NN / 64, BB * 2), 256, 0, stream>>>(X, Y, ymean, XnT, YnT);

    dim3 ggrid(512);   // 4b x 64ip x 2jh, XCD-pinned decode in-kernel, 2 blocks/CU
    krow<1><<<ggrid, 256, 0, stream>>>(XnT, YnT, rowA, rowB, partial, colpart);
    kredA<<<dim3(BB * NN / 256), 256, 0, stream>>>(partial, rowA);
    krow<2><<<ggrid, 256, 0, stream>>>(XnT, YnT, rowA, rowB, partial, colpart);
    kredB<<<dim3(BB * NN / 256), 256, 0, stream>>>(partial, rowB);
    krow<3><<<ggrid, 256, 0, stream>>>(XnT, YnT, rowA, rowB, partial, colpart);
    kredC<<<dim3(NN / 256, BB), 256, 0, stream>>>(colpart, sums);
    kfinal2<<<dim3(1), 64, 0, stream>>>(sums, out);
}

// Round 8
// 171.376 us; speedup vs baseline: 1.3045x; 1.3045x over previous
//
#include <hip/hip_runtime.h>
#include <hip/hip_fp16.h>
#include <cstdint>
#include <cstddef>

#define BB 4
#define CC 256
#define NN 4096
#define EPS_NORM 2.220446049250313e-16f
#define EPS_MIN 1e-5f

typedef __attribute__((ext_vector_type(8))) short short8;
typedef __attribute__((ext_vector_type(4))) float floatx4;
typedef __attribute__((ext_vector_type(4))) unsigned int uint4v;
typedef __attribute__((ext_vector_type(2))) _Float16 half2v;

__device__ __forceinline__ unsigned short f2bf(float f) {
    unsigned u = __float_as_uint(f);
    u += 0x7FFFu + ((u >> 16) & 1u);   // RNE
    return (unsigned short)(u >> 16);
}
__device__ __forceinline__ void async_cp16(const void* g, void* l) {
    __builtin_amdgcn_global_load_lds(
        (const __attribute__((address_space(1))) unsigned int*)g,
        (__attribute__((address_space(3))) unsigned int*)l, 16, 0, 0);
}

// ---- K1: per-channel spatial mean of Y (float4); also zero sums ------------
__global__ void kmean(const float* __restrict__ Y, float* __restrict__ ymean,
                      float* __restrict__ sums) {
    if (blockIdx.x == 0 && threadIdx.x < BB) sums[threadIdx.x] = 0.f;
    int bc = blockIdx.x;  // b*CC + c
    const float4* p = (const float4*)(Y + (size_t)bc * NN);
    float s = 0.f;
    for (int k = threadIdx.x; k < NN / 4; k += 256) {
        float4 v = p[k];
        s += (v.x + v.y) + (v.z + v.w);
    }
    __shared__ float red[256];
    red[threadIdx.x] = s; __syncthreads();
    for (int st = 128; st > 0; st >>= 1) {
        if (threadIdx.x < st) red[threadIdx.x] += red[threadIdx.x + st];
        __syncthreads();
    }
    if (threadIdx.x == 0) ymean[bc] = red[0] * (1.0f / NN);
}

// ------- K2: fused norm + normalize + transpose -> bf16 [B,N,C] -------------
__global__ __launch_bounds__(256)
void kfuse(const float* __restrict__ X, const float* __restrict__ Y,
           const float* __restrict__ ymean,
           unsigned short* __restrict__ XnT, unsigned short* __restrict__ YnT) {
    int b = blockIdx.y >> 1, which = blockIdx.y & 1;
    const float* src = which ? Y : X;
    unsigned short* dst = which ? YnT : XnT;
    int n0 = blockIdx.x * 64;
    int tx = threadIdx.x & 63, ty = threadIdx.x >> 6;
    __shared__ float mean_s[CC];
    __shared__ float red[4][64];
    __shared__ float invn[64];
    __shared__ float tile[64][65];
    mean_s[threadIdx.x] = ymean[b * CC + threadIdx.x];
    __syncthreads();
    float vreg[64];
    float s = 0.f;
    #pragma unroll
    for (int k = 0; k < 64; ++k) {
        int c = ty + 4 * k;
        float v = src[(((size_t)b * CC + c) << 12) + n0 + tx] - mean_s[c];
        vreg[k] = v;
        s += v * v;
    }
    red[ty][tx] = s; __syncthreads();
    if (ty == 0) {
        float t = red[0][tx] + red[1][tx] + red[2][tx] + red[3][tx];
        invn[tx] = 1.0f / (sqrtf(t) + EPS_NORM);
    }
    __syncthreads();
    float inv = invn[tx];
    for (int cb = 0; cb < 4; ++cb) {
        if (cb) __syncthreads();
        #pragma unroll
        for (int kk = 0; kk < 16; ++kk) {
            tile[4 * kk + ty][tx] = vreg[cb * 16 + kk] * inv;
        }
        __syncthreads();
        #pragma unroll
        for (int it = 0; it < 16; ++it) {
            int nl = ty + it * 4;
            dst[((size_t)(b * NN + n0 + nl)) * CC + cb * 64 + tx] = f2bf(tile[tx][nl]);
        }
    }
}

// ======================= FULL PATH: materialize S ============================
// kgemm0: S = A.B^T tile 128x128, XOR-swizzled async-staged LDS, 4 blocks/CU.
// XCD-pinned decode (xcd = bid&7 -> batch, i-half): FETCH 37 -> ~20 MB (R2).
// S stored fp16 with NON-TEMPORAL 16B stores (write-once, read-once by kstats).
__global__ __launch_bounds__(256, 4)
void kgemm0(const unsigned short* __restrict__ Aptr, const unsigned short* __restrict__ Bptr,
            __half* __restrict__ dmat) {
    const int bid = blockIdx.x;
    const int xcd = bid & 7, q = bid >> 3;
    const int b = xcd >> 1;
    const int by = (xcd & 1) * 16 + (q >> 5);
    const int bx = q & 31;
    const int i0 = by * 128, j0 = bx * 128;
    const int tid = threadIdx.x, lane = tid & 63, wave = tid >> 6;
    const int wm = wave >> 1, wn = wave & 1, l15 = lane & 15, quad = lane >> 4;
    __shared__ unsigned short smem[17408];   // staging 32768 B | fp16 tile 128x136
    unsigned short* As = smem;
    unsigned short* Bs = smem + 128 * 64;
    floatx4 acc[4][4];
    #pragma unroll
    for (int ms = 0; ms < 4; ++ms)
        #pragma unroll
        for (int ns = 0; ns < 4; ++ns) acc[ms][ns] = (floatx4){0.f, 0.f, 0.f, 0.f};

    const unsigned short* gA = Aptr + ((size_t)b * NN + i0) * CC;
    const unsigned short* gB = Bptr + ((size_t)b * NN + j0) * CC;
    const int rl = lane >> 3, pos = lane & 7;
    const int cb = pos ^ rl;
    const unsigned short* gAl = gA + (size_t)(wave * 32 + rl) * CC + cb * 8;
    const unsigned short* gBl = gB + (size_t)(wave * 32 + rl) * CC + cb * 8;
    unsigned short* lA = As + (wave * 32) * 64;
    unsigned short* lB = Bs + (wave * 32) * 64;

    for (int kc = 0; kc < CC; kc += 64) {
        #pragma unroll
        for (int seg = 0; seg < 4; ++seg) {
            async_cp16(gAl + (size_t)seg * 8 * CC + kc, lA + seg * 8 * 64);
            async_cp16(gBl + (size_t)seg * 8 * CC + kc, lB + seg * 8 * 64);
        }
        __syncthreads();
        #pragma unroll
        for (int kk = 0; kk < 64; kk += 32) {
            short8 af[4], bf[4];
            int sw = (quad + (kk >> 3)) ^ (l15 & 7);
            #pragma unroll
            for (int s = 0; s < 4; ++s) {
                af[s] = *(const short8*)&As[(wm * 64 + s * 16 + l15) * 64 + (sw << 3)];
                bf[s] = *(const short8*)&Bs[(wn * 64 + s * 16 + l15) * 64 + (sw << 3)];
            }
            #pragma unroll
            for (int ms = 0; ms < 4; ++ms)
                #pragma unroll
                for (int ns = 0; ns < 4; ++ns)
                    acc[ms][ns] = __builtin_amdgcn_mfma_f32_16x16x32_bf16(af[ms], bf[ns], acc[ms][ns], 0, 0, 0);
        }
        __syncthreads();
    }

    __half* tile = (__half*)smem;
    #pragma unroll
    for (int ms = 0; ms < 4; ++ms)
        #pragma unroll
        for (int r = 0; r < 4; ++r) {
            int il = wm * 64 + ms * 16 + quad * 4 + r;
            #pragma unroll
            for (int ns = 0; ns < 4; ++ns)
                tile[il * 136 + wn * 64 + ns * 16 + l15] = __float2half(acc[ms][ns][r]);
        }
    __syncthreads();
    __half* dB = dmat + (size_t)b * NN * NN;
    #pragma unroll
    for (int it = 0; it < 8; ++it) {
        int idx = tid + it * 256;
        int row = idx >> 4, col = (idx & 15) * 8;
        __builtin_nontemporal_store(*(const uint4v*)&tile[row * 136 + col],
                                    (uint4v*)&dB[(size_t)(i0 + row) * NN + j0 + col]);
    }
}

// ------- kstats: fused row-stats + column-max partials. 16 rows/block. ------
// One nt read of S; rowmax -> alpha -> exp-sum -> gamma -> colmax, all in regs.
__global__ __launch_bounds__(512, 2)
void kstats(const __half* __restrict__ smat, float* __restrict__ partial) {
    int b = blockIdx.y, rg = blockIdx.x;
    const __half* base = smat + (size_t)b * NN * NN + (size_t)rg * 16 * NN;
    float* pout = partial + ((size_t)b * 256 + rg) * NN;
    int t = threadIdx.x, wv = t >> 6, ln = t & 63;
    uint4v v[16];
    #pragma unroll
    for (int r = 0; r < 16; ++r)
        v[r] = __builtin_nontemporal_load((const uint4v*)&base[(size_t)r * NN + t * 8]);
    __shared__ float wred[16][8];
    __shared__ float alphaS[16], gamS[16];
    // pass A: per-row max of s, packed fp16
    #pragma unroll
    for (int r = 0; r < 16; ++r) {
        half2v m2 = __builtin_bit_cast(half2v, v[r][0]);
        #pragma unroll
        for (int e = 1; e < 4; ++e)
            m2 = __builtin_elementwise_max(m2, __builtin_bit_cast(half2v, v[r][e]));
        float mx = fmaxf((float)m2[0], (float)m2[1]);
        mx = fmaxf(mx, __shfl_xor(mx, 1));  mx = fmaxf(mx, __shfl_xor(mx, 2));
        mx = fmaxf(mx, __shfl_xor(mx, 4));  mx = fmaxf(mx, __shfl_xor(mx, 8));
        mx = fmaxf(mx, __shfl_xor(mx, 16)); mx = fmaxf(mx, __shfl_xor(mx, 32));
        if (ln == 0) wred[r][wv] = mx;
    }
    __syncthreads();
    if (t < 16) {
        float mx = wred[t][0];
        #pragma unroll
        for (int k = 1; k < 8; ++k) mx = fmaxf(mx, wred[t][k]);
        alphaS[t] = 10.0f / ((1.0f - mx) + EPS_MIN);
    }
    __syncthreads();
    // pass B: sum of exp((10-a) + a*s)
    #pragma unroll
    for (int r = 0; r < 16; ++r) {
        float a = alphaS[r], c = 10.0f - a;
        float s = 0.f;
        #pragma unroll
        for (int e = 0; e < 4; ++e) {
            float2 f = __half22float2(__builtin_bit_cast(__half2, v[r][e]));
            s += __expf(fmaf(a, f.x, c)) + __expf(fmaf(a, f.y, c));
        }
        s += __shfl_xor(s, 1);  s += __shfl_xor(s, 2);  s += __shfl_xor(s, 4);
        s += __shfl_xor(s, 8);  s += __shfl_xor(s, 16); s += __shfl_xor(s, 32);
        if (ln == 0) wred[r][wv] = s;
    }
    __syncthreads();
    if (t < 16) {
        float sum = wred[t][0];
        #pragma unroll
        for (int k = 1; k < 8; ++k) sum += wred[t][k];
        gamS[t] = (10.0f - logf(sum)) - alphaS[t];   // t_ij = gam + a*s
    }
    __syncthreads();
    // pass C: per-column max over the 16 rows
    float pm[8];
    #pragma unroll
    for (int e = 0; e < 8; ++e) pm[e] = -1e30f;
    #pragma unroll
    for (int r = 0; r < 16; ++r) {
        float a = alphaS[r], g = gamS[r];
        #pragma unroll
        for (int e = 0; e < 4; ++e) {
            float2 f = __half22float2(__builtin_bit_cast(__half2, v[r][e]));
            pm[2 * e]     = fmaxf(pm[2 * e],     fmaf(a, f.x, g));
            pm[2 * e + 1] = fmaxf(pm[2 * e + 1], fmaf(a, f.y, g));
        }
    }
    *(float4*)&pout[t * 8]     = make_float4(pm[0], pm[1], pm[2], pm[3]);
    *(float4*)&pout[t * 8 + 4] = make_float4(pm[4], pm[5], pm[6], pm[7]);
}

// ------- reduce partials: colmax over rowgroups -> exp -> sum per batch -----
__global__ __launch_bounds__(1024)
void kred1(const float* __restrict__ partial, float* __restrict__ sums) {
    int b = blockIdx.y;
    int jl = threadIdx.x & 255;
    int j = blockIdx.x * 256 + jl;
    int slice = threadIdx.x >> 8;
    const float* p = partial + ((size_t)b * 256 + slice * 64) * NN + j;
    float m = -1e30f;
    #pragma unroll 4
    for (int pb = 0; pb < 64; ++pb) m = fmaxf(m, p[(size_t)pb * NN]);
    __shared__ float sl[4][256];
    sl[slice][jl] = m;
    __syncthreads();
    __shared__ float red[256];
    if (threadIdx.x < 256) {
        float mm = fmaxf(fmaxf(sl[0][threadIdx.x], sl[1][threadIdx.x]),
                         fmaxf(sl[2][threadIdx.x], sl[3][threadIdx.x]));
        red[threadIdx.x] = __expf(mm);
    }
    __syncthreads();
    for (int st = 128; st > 0; st >>= 1) {
        if (threadIdx.x < st) red[threadIdx.x] += red[threadIdx.x + st];
        __syncthreads();
    }
    if (threadIdx.x == 0) atomicAdd(&sums[b], red[0]);
}

__global__ void kfinal2(const float* __restrict__ sums, float* __restrict__ out) {
    int t = threadIdx.x;
    if (t < BB) out[t] = logf((float)NN) - logf(sums[t]);
}

// ================== FALLBACK PATH: 3-pass recompute (R7) =====================
template <int MODE>
__global__ __launch_bounds__(256, 2)
void krow(const unsigned short* __restrict__ Aptr, const unsigned short* __restrict__ Bptr,
          const float* __restrict__ rowA, const float* __restrict__ rowB,
          float* __restrict__ partial, float* __restrict__ colpart) {
    const int bid = blockIdx.x;
    const int b = (bid >> 1) & 3;
    const int jh = bid & 1;
    const int ip = bid >> 3;
    const int i0 = ip * 64, j0 = jh * 2048;
    const int tid = threadIdx.x, lane = tid & 63, wave = tid >> 6;
    const int wm = wave >> 1, wn = wave & 1, l15 = lane & 15, quad = lane >> 4;

    __shared__ unsigned short Bs[4 * 8192];
    __shared__ float scr3[4 * 4 * 64];

    float pax[2][4], pay[2][4];
    if (MODE >= 2) {
        #pragma unroll
        for (int m = 0; m < 2; ++m)
            #pragma unroll
            for (int r = 0; r < 4; ++r) {
                const int i = b * NN + i0 + wm * 32 + m * 16 + quad * 4 + r;
                const float a = rowA[i];
                pax[m][r] = a;
                pay[m][r] = (MODE == 2) ? (10.0f - a) : (rowB[i] - a);
            }
    }

    const int rl = lane >> 3, pos = lane & 7, cbx = pos ^ rl;
    {
        const unsigned short* gAl = Aptr + ((size_t)b * NN + i0 + rl) * CC + wave * 64 + cbx * 8;
        unsigned short* lA = Bs + 2 * 8192 + wave * 4096;
        #pragma unroll
        for (int seg = 0; seg < 8; ++seg)
            async_cp16(gAl + (size_t)seg * 8 * CC, lA + seg * 8 * 64);
    }
    const unsigned short* gBl = Bptr + ((size_t)b * NN + j0 + wave * 32 + rl) * CC + cbx * 8;
#define STAGE_B(s) do { \
        const unsigned short* gs_ = gBl + (size_t)((s) >> 2) * 128 * CC + ((s) & 3) * 64; \
        unsigned short* lb_ = Bs + ((s) & 3) * 8192 + wave * 2048; \
        async_cp16(gs_ + (size_t)0 * 8 * CC, lb_ + 0 * 8 * 64); \
        async_cp16(gs_ + (size_t)1 * 8 * CC, lb_ + 1 * 8 * 64); \
        async_cp16(gs_ + (size_t)2 * 8 * CC, lb_ + 2 * 8 * 64); \
        async_cp16(gs_ + (size_t)3 * 8 * CC, lb_ + 3 * 8 * 64); \
    } while (0)

    STAGE_B(0);
    STAGE_B(1);
    __syncthreads();

    short8 af[4][4];
    {
        const unsigned short* Ar = Bs + 2 * 8192;
        #pragma unroll
        for (int kc = 0; kc < 4; ++kc)
            #pragma unroll
            for (int h = 0; h < 2; ++h)
                #pragma unroll
                for (int m = 0; m < 2; ++m)
                    af[kc][h * 2 + m] = *(const short8*)&Ar[kc * 4096 +
                        (wm * 32 + m * 16 + l15) * 64 + (((quad + 4 * h) ^ (l15 & 7)) << 3)];
    }
    __syncthreads();
    STAGE_B(2);
    STAGE_B(3);

    floatx4 acc[2][4];
    #pragma unroll
    for (int m = 0; m < 2; ++m)
        #pragma unroll
        for (int ns = 0; ns < 4; ++ns) acc[m][ns] = (floatx4){0.f, 0.f, 0.f, 0.f};
    float rm[2][4];
    #pragma unroll
    for (int m = 0; m < 2; ++m)
        #pragma unroll
        for (int r = 0; r < 4; ++r) rm[m][r] = (MODE == 1) ? 1e30f : 0.f;

#define FLUSH(g_) do { \
        const int t4_ = tid * 4; \
        const int wg_ = t4_ >> 8, jtl_ = (t4_ >> 6) & 3, c_ = t4_ & 63; \
        float4 fv_ = *(const float4*)&scr3[t4_]; \
        *(float4*)&colpart[((size_t)(b * 128 + ip * 2 + (wg_ >> 1))) * NN + j0 + \
                           ((g_) * 4 + jtl_) * 128 + (wg_ & 1) * 64 + c_] = fv_; \
    } while (0)

#define STEP_BODY(ut_, kc_, VMN_, DOSTAGE_) do { \
        asm volatile("" ::: "memory"); \
        __builtin_amdgcn_s_barrier(); \
        asm volatile("" ::: "memory"); \
        if (MODE == 3 && (kc_) == 0 && (ut_) > 0 && ((ut_) & 3) == 0) FLUSH((ut_) / 4 - 1); \
        if (DOSTAGE_) STAGE_B((ut_) * 4 + (kc_) + 3); \
        asm volatile("s_waitcnt vmcnt(" #VMN_ ")" ::: "memory"); \
        __builtin_amdgcn_s_barrier(); \
        asm volatile("" ::: "memory"); \
        const unsigned short* Bp_ = Bs + (kc_) * 8192; \
        _Pragma("unroll") \
        for (int h = 0; h < 2; ++h) { \
            short8 bf[4]; \
            const int sw_ = (((quad + 4 * h) ^ (l15 & 7)) << 3); \
            _Pragma("unroll") \
            for (int s = 0; s < 4; ++s) \
                bf[s] = *(const short8*)&Bp_[(wn * 64 + s * 16 + l15) * 64 + sw_]; \
            _Pragma("unroll") \
            for (int m = 0; m < 2; ++m) \
                _Pragma("unroll") \
                for (int ns = 0; ns < 4; ++ns) \
                    acc[m][ns] = __builtin_amdgcn_mfma_f32_16x16x32_bf16( \
                        af[kc_][h * 2 + m], bf[ns], acc[m][ns], 0, 0, 0); \
        } \
        if ((kc_) == 3) { \
            const int jt_ = (ut_); \
            if (MODE == 1) { \
                _Pragma("unroll") \
                for (int m = 0; m < 2; ++m) \
                    _Pragma("unroll") \
                    for (int r = 0; r < 4; ++r) { \
                        float mn_ = 1.0f - acc[m][0][r]; \
                        _Pragma("unroll") \
                        for (int ns = 1; ns < 4; ++ns) mn_ = fminf(mn_, 1.0f - acc[m][ns][r]); \
                        rm[m][r] = fminf(rm[m][r], mn_); \
                    } \
            } else if (MODE == 2) { \
                _Pragma("unroll") \
                for (int m = 0; m < 2; ++m) \
                    _Pragma("unroll") \
                    for (int r = 0; r < 4; ++r) { \
                        float s_ = 0.f; \
                        _Pragma("unroll") \
                        for (int ns = 0; ns < 4; ++ns) \
                            s_ += __expf(fmaf(pax[m][r], acc[m][ns][r], pay[m][r])); \
                        rm[m][r] += s_; \
                    } \
            } else { \
                _Pragma("unroll") \
                for (int ns = 0; ns < 4; ++ns) { \
                    float v_ = -1e30f; \
                    _Pragma("unroll") \
                    for (int m = 0; m < 2; ++m) \
                        _Pragma("unroll") \
                        for (int r = 0; r < 4; ++r) \
                            v_ = fmaxf(v_, fmaf(pax[m][r], acc[m][ns][r], pay[m][r])); \
                    v_ = fmaxf(v_, __shfl_xor(v_, 16)); \
                    v_ = fmaxf(v_, __shfl_xor(v_, 32)); \
                    if (quad == 0) \
                        scr3[((wm * 2 + wn) * 4 + (jt_ & 3)) * 64 + ns * 16 + l15] = v_; \
                } \
                asm volatile("s_waitcnt lgkmcnt(0)" ::: "memory"); \
            } \
            _Pragma("unroll") \
            for (int m = 0; m < 2; ++m) \
                _Pragma("unroll") \
                for (int ns = 0; ns < 4; ++ns) acc[m][ns] = (floatx4){0.f, 0.f, 0.f, 0.f}; \
        } \
    } while (0)

    for (int ut = 0; ut < 15; ++ut) {
        STEP_BODY(ut, 0, 12, (ut > 0));
        STEP_BODY(ut, 1, 12, true);
        STEP_BODY(ut, 2, 12, true);
        STEP_BODY(ut, 3, 12, true);
    }
    STEP_BODY(15, 0, 12, true);
    STEP_BODY(15, 1, 8,  false);
    STEP_BODY(15, 2, 4,  false);
    STEP_BODY(15, 3, 0,  false);
#undef STEP_BODY
#undef STAGE_B

    if (MODE <= 2) {
        #pragma unroll
        for (int m = 0; m < 2; ++m)
            #pragma unroll
            for (int r = 0; r < 4; ++r) {
                float v = rm[m][r];
                if (MODE == 1) {
                    v = fminf(v, __shfl_xor(v, 1)); v = fminf(v, __shfl_xor(v, 2));
                    v = fminf(v, __shfl_xor(v, 4)); v = fminf(v, __shfl_xor(v, 8));
                } else {
                    v += __shfl_xor(v, 1); v += __shfl_xor(v, 2);
                    v += __shfl_xor(v, 4); v += __shfl_xor(v, 8);
                }
                if (l15 == 0)
                    scr3[(wm * 32 + m * 16 + quad * 4 + r) * 2 + wn] = v;
            }
        __syncthreads();
        if (tid < 64) {
            float v = (MODE == 1) ? fminf(scr3[tid * 2], scr3[tid * 2 + 1])
                                  : (scr3[tid * 2] + scr3[tid * 2 + 1]);
            partial[((size_t)(b * 2 + jh)) * NN + i0 + tid] = v;
        }
    } else {
        __syncthreads();
        FLUSH(3);
    }
#undef FLUSH
}

__global__ void kredA(const float* __restrict__ partial, float* __restrict__ rowA) {
    int idx = blockIdx.x * 256 + threadIdx.x;
    int b = idx >> 12, i = idx & (NN - 1);
    float m = fminf(partial[((size_t)(b * 2)) * NN + i],
                    partial[((size_t)(b * 2 + 1)) * NN + i]);
    rowA[idx] = 10.0f / (m + EPS_MIN);
}
__global__ void kredB(const float* __restrict__ partial, float* __restrict__ rowB) {
    int idx = blockIdx.x * 256 + threadIdx.x;
    int b = idx >> 12, i = idx & (NN - 1);
    float s = partial[((size_t)(b * 2)) * NN + i] +
              partial[((size_t)(b * 2 + 1)) * NN + i];
    rowB[idx] = 10.0f - __logf(s);
}
__global__ void kredC(const float* __restrict__ colpart, float* __restrict__ sums) {
    int b = blockIdx.y;
    int j = blockIdx.x * 256 + threadIdx.x;
    float m = -1e30f;
    #pragma unroll 4
    for (int p = 0; p < 128; ++p)
        m = fmaxf(m, colpart[((size_t)(b * 128 + p)) * NN + j]);
    float e = __expf(m);
    __shared__ float red[256];
    red[threadIdx.x] = e; __syncthreads();
    for (int st = 128; st > 0; st >>= 1) {
        if (threadIdx.x < st) red[threadIdx.x] += red[threadIdx.x + st];
        __syncthreads();
    }
    if (threadIdx.x == 0) atomicAdd(&sums[b], red[0]);
}

extern "C" void kernel_launch(void* const* d_in, const int* in_sizes, int n_in,
                              void* d_out, int out_size, void* d_ws, size_t ws_size,
                              hipStream_t stream) {
    const float* X = (const float*)d_in[0];
    const float* Y = (const float*)d_in[1];
    float* out = (float*)d_out;

    char* w = (char*)d_ws;
    float* ymean = (float*)(w + 0);          //   4 KiB
    float* sums  = (float*)(w + 4096);       //  tiny

    // ---- full-path layout ----
    unsigned short* XnT = (unsigned short*)(w + 8192);       //  8 MiB
    unsigned short* YnT = (unsigned short*)(w + 8396800);    //  8 MiB
    float* partial      = (float*)(w + 16785408);            // 16 MiB
    __half* dmat        = (__half*)(w + 33562624);           // 134 MiB
    const size_t full_need = 33562624 + (size_t)BB * NN * NN * 2;  // ~167.8 MB

    if (ws_size >= full_need) {
        kmean<<<dim3(BB * CC), 256, 0, stream>>>(Y, ymean, sums);
        kfuse<<<dim3(NN / 64, BB * 2), 256, 0, stream>>>(X, Y, ymean, XnT, YnT);
        kgemm0<<<dim3(4096), 256, 0, stream>>>(XnT, YnT, dmat);
        kstats<<<dim3(NN / 16, BB), 512, 0, stream>>>(dmat, partial);
        kred1<<<dim3(NN / 256, BB), 1024, 0, stream>>>(partial, sums);
        kfinal2<<<dim3(1), 64, 0, stream>>>(sums, out);
    } else {
        // ---- fallback: R7 3-pass recompute (needs ~25.4 MB) ----
        float* rowA          = (float*)(w + 8192);
        float* rowB          = (float*)(w + 73728);
        float* partialF      = (float*)(w + 139264);
        float* colpart       = (float*)(w + 270336);
        unsigned short* XnTf = (unsigned short*)(w + 8658944);
        unsigned short* YnTf = (unsigned short*)(w + 17047552);

        kmean<<<dim3(BB * CC), 256, 0, stream>>>(Y, ymean, sums);
        kfuse<<<dim3(NN / 64, BB * 2), 256, 0, stream>>>(X, Y, ymean, XnTf, YnTf);
        dim3 ggrid(512);
        krow<1><<<ggrid, 256, 0, stream>>>(XnTf, YnTf, rowA, rowB, partialF, colpart);
        kredA<<<dim3(BB * NN / 256), 256, 0, stream>>>(partialF, rowA);
        krow<2><<<ggrid, 256, 0, stream>>>(XnTf, YnTf, rowA, rowB, partialF, colpart);
        kredB<<<dim3(BB * NN / 256), 256, 0, stream>>>(partialF, rowB);
        krow<3><<<ggrid, 256, 0, stream>>>(XnTf, YnTf, rowA, rowB, partialF, colpart);
        kredC<<<dim3(NN / 256, BB), 256, 0, stream>>>(colpart, sums);
        kfinal2<<<dim3(1), 64, 0, stream>>>(sums, out);
    }
}